// Round 2
// baseline (2418.930 us; speedup 1.0000x reference)
//
#include <hip/hip_runtime.h>

#define S_LEN 2048
#define B_SZ  64
#define D_IN  128
#define H_SZ  128
#define G4    512   // 4*H

typedef __attribute__((ext_vector_type(4))) float     floatx4;
typedef __attribute__((ext_vector_type(2))) float     floatx2;
typedef __attribute__((ext_vector_type(8))) _Float16  half8;
typedef __attribute__((ext_vector_type(2))) _Float16  half2_t;

// DPP quad_perm helper (VALU pipe). CTRL: xor1=0xB1, xor2=0x4E.
template<int CTRL>
__device__ __forceinline__ float qperm(float v) {
  return __int_as_float(
      __builtin_amdgcn_mov_dpp(__float_as_int(v), CTRL, 0xF, 0xF, true));
}

// half2 extraction from half8 — register aliasing, no union round-trip
template<int P>
__device__ __forceinline__ half2_t h2ext(half8 v) {
  return __builtin_shufflevector(v, v, 2 * P, 2 * P + 1);
}

// Workgroup barrier that drains ONLY lgkmcnt (LDS), leaving global loads/
// stores (vmcnt) in flight. __syncthreads() would drain vmcnt(0) each step.
__device__ __forceinline__ void lds_barrier() {
  asm volatile("s_waitcnt lgkmcnt(0)\n\ts_barrier" ::: "memory");
}

// ---------------------------------------------------------------------------
// Kernel 1: gates_x[sb][n] = (sum_k X[sb][k]*W_ih[n][k] + b[n]) * sc(type),
// stored f16.  sc = -log2e for i,f,o; -2log2e for g (folds the sigmoid/tanh
// exp2 scaling into the data so lstm_rev's activation chain is shorter).
// ---------------------------------------------------------------------------
__global__ __launch_bounds__(256) void gx_gemm(
    const float* __restrict__ X,       // [S*B][128]
    const float* __restrict__ Wih,     // [512][128]
    const float* __restrict__ bias,    // [512]
    _Float16* __restrict__ gx)         // [S*B][512] f16, pre-scaled
{
  __shared__ _Float16 Wl[128][136];
  const int tid  = threadIdx.x;
  const int lane = tid & 63;
  const int wv   = tid >> 6;
  const int R0   = blockIdx.x * 256;
  const int m    = lane & 15;
  const int q    = lane >> 4;

  const float LOG2E = 1.4426950408889634f;

  half8 afrag[4][4];
  #pragma unroll
  for (int rg = 0; rg < 4; ++rg) {
    const float* xrow = X + (size_t)(R0 + rg * 64 + wv * 16 + m) * D_IN;
    #pragma unroll
    for (int kf = 0; kf < 4; ++kf) {
      const int k0 = kf * 32 + q * 8;
      floatx4 v0 = *(const floatx4*)(xrow + k0);
      floatx4 v1 = *(const floatx4*)(xrow + k0 + 4);
      half8 a;
      a[0] = (_Float16)v0.x; a[1] = (_Float16)v0.y;
      a[2] = (_Float16)v0.z; a[3] = (_Float16)v0.w;
      a[4] = (_Float16)v1.x; a[5] = (_Float16)v1.y;
      a[6] = (_Float16)v1.z; a[7] = (_Float16)v1.w;
      afrag[rg][kf] = a;
    }
  }

  for (int nc = 0; nc < 4; ++nc) {      // gate-type chunk (128 gate rows)
    const float sc = (nc == 2) ? (-2.0f * LOG2E) : (-LOG2E);
    __syncthreads();
    for (int i = tid; i < 128 * 32; i += 256) {
      const int row = i >> 5;
      const int c4  = (i & 31) * 4;
      floatx4 v = *(const floatx4*)(Wih + ((size_t)nc * 128 + row) * D_IN + c4);
      Wl[row][c4 + 0] = (_Float16)v.x;
      Wl[row][c4 + 1] = (_Float16)v.y;
      Wl[row][c4 + 2] = (_Float16)v.z;
      Wl[row][c4 + 3] = (_Float16)v.w;
    }
    __syncthreads();

    #pragma unroll
    for (int nt = 0; nt < 8; ++nt) {
      const int n0  = nc * 128 + nt * 16;
      const int nlo = nt * 16 + m;
      const float bv = bias[n0 + m];
      half8 bfrag[4];
      #pragma unroll
      for (int kf = 0; kf < 4; ++kf)
        bfrag[kf] = *(const half8*)(&Wl[nlo][kf * 32 + q * 8]);
      #pragma unroll
      for (int rg = 0; rg < 4; ++rg) {
        floatx4 acc = {bv, bv, bv, bv};
        #pragma unroll
        for (int kf = 0; kf < 4; ++kf)
          acc = __builtin_amdgcn_mfma_f32_16x16x32_f16(afrag[rg][kf],
                                                       bfrag[kf], acc, 0, 0, 0);
        // C layout: col = lane&15, row = q*4 + reg
        _Float16* gp =
            gx + (size_t)(R0 + rg * 64 + wv * 16 + q * 4) * G4 + n0 + m;
        #pragma unroll
        for (int r = 0; r < 4; ++r)
          gp[(size_t)r * G4] = (_Float16)(acc[r] * sc);
      }
    }
  }
}

// ---------------------------------------------------------------------------
// Kernel 2: reverse-time recurrence. One WG per TWO batches (32 WGs x 512
// threads): two independent gate pipelines per thread fill the latency gaps
// (LDS round-trip, activation chain). Weights live in 16 NAMED half8 VGPRs
// (w00..w33) — NOT an array, NOT passed by reference: round-1's w[4][4]
// by-ref into an inlined fn was scratch-demoted (VGPR_Count=60, 1.73x
// regression). One barrier covers two batch-steps. gx/time prefetch at
// distance-2 substeps (> HBM miss latency ~900cy).
// types: 0=i 1=f 2=g 3=o
// ---------------------------------------------------------------------------
__device__ __forceinline__ float fd(half2_t a, half2_t b, float c) {
  return __builtin_amdgcn_fdot2(a, b, c, false);
}

__device__ __forceinline__ half8 wcvt(const float* __restrict__ p, float sc) {
  floatx4 v0 = *(const floatx4*)p;
  floatx4 v1 = *(const floatx4*)(p + 4);
  half8 h;
  h[0] = (_Float16)(v0.x * sc); h[1] = (_Float16)(v0.y * sc);
  h[2] = (_Float16)(v0.z * sc); h[3] = (_Float16)(v0.w * sc);
  h[4] = (_Float16)(v1.x * sc); h[5] = (_Float16)(v1.y * sc);
  h[6] = (_Float16)(v1.z * sc); h[7] = (_Float16)(v1.w * sc);
  return h;
}

// DOT8 over one h-fragment HV with the four gate-type weight frags WA..WD
// (WA = gate i, WB = f, WC = g, WD = o).
#define DOT8(HV, WA, WB, WC, WD)                                              \
  {                                                                           \
    q0a = fd(h2ext<0>(HV), h2ext<0>(WA), q0a);                                \
    q1a = fd(h2ext<0>(HV), h2ext<0>(WB), q1a);                                \
    q2a = fd(h2ext<0>(HV), h2ext<0>(WC), q2a);                                \
    q3a = fd(h2ext<0>(HV), h2ext<0>(WD), q3a);                                \
    q0a = fd(h2ext<1>(HV), h2ext<1>(WA), q0a);                                \
    q1a = fd(h2ext<1>(HV), h2ext<1>(WB), q1a);                                \
    q2a = fd(h2ext<1>(HV), h2ext<1>(WC), q2a);                                \
    q3a = fd(h2ext<1>(HV), h2ext<1>(WD), q3a);                                \
    q0b = fd(h2ext<2>(HV), h2ext<2>(WA), q0b);                                \
    q1b = fd(h2ext<2>(HV), h2ext<2>(WB), q1b);                                \
    q2b = fd(h2ext<2>(HV), h2ext<2>(WC), q2b);                                \
    q3b = fd(h2ext<2>(HV), h2ext<2>(WD), q3b);                                \
    q0b = fd(h2ext<3>(HV), h2ext<3>(WA), q0b);                                \
    q1b = fd(h2ext<3>(HV), h2ext<3>(WB), q1b);                                \
    q2b = fd(h2ext<3>(HV), h2ext<3>(WC), q2b);                                \
    q3b = fd(h2ext<3>(HV), h2ext<3>(WD), q3b);                                \
  }

// Full gate pipeline for one batch, one step. HR: LDS prev-h (128 halfs).
// GXV/TMV: prefetched gx (pre-scaled) and time. CVAR: running c (updated).
// HVAR: receives h (meaningful on tt==3 lanes). All weight/lane constants
// (w00..w33, wt, bt, am, aa, odd, tt, LOG2E) come from enclosing scope.
#define GATE(HR, GXV, TMV, CVAR, HVAR)                                        \
  {                                                                           \
    half8 hv0 = *(const half8*)((HR) + 0 * 32 + tt * 8);                      \
    half8 hv1 = *(const half8*)((HR) + 1 * 32 + tt * 8);                      \
    half8 hv2 = *(const half8*)((HR) + 2 * 32 + tt * 8);                      \
    half8 hv3 = *(const half8*)((HR) + 3 * 32 + tt * 8);                      \
    float q0a = 0.f, q0b = 0.f, q1a = 0.f, q1b = 0.f;                         \
    float q2a = 0.f, q2b = 0.f, q3a = 0.f, q3b = 0.f;                         \
    DOT8(hv0, w00, w10, w20, w30);                                            \
    DOT8(hv1, w01, w11, w21, w31);                                            \
    DOT8(hv2, w02, w12, w22, w32);                                            \
    DOT8(hv3, w03, w13, w23, w33);                                            \
    float a0 = q0a + q0b, a1 = q1a + q1b, a2 = q2a + q2b, a3 = q3a + q3b;     \
    a0 += qperm<0xB1>(a0); a1 += qperm<0xB1>(a1);                             \
    a2 += qperm<0xB1>(a2); a3 += qperm<0xB1>(a3);                             \
    a0 += qperm<0x4E>(a0); a1 += qperm<0x4E>(a1);                             \
    a2 += qperm<0x4E>(a2); a3 += qperm<0x4E>(a3);                             \
    float pre = (tt & 1) ? ((tt & 2) ? a3 : a1) : ((tt & 2) ? a2 : a0);       \
    pre += (GXV);  /* already scaled by -log2e (or -2log2e for g) */          \
    const float e  = __builtin_amdgcn_exp2f(pre);                             \
    const float v  = fmaf(am, __builtin_amdgcn_rcpf(1.0f + e), aa);           \
    float z = fmaf((TMV), wt, bt);           /* = -log2e*(t*w_t+b_t) */       \
    z = fminf(z, 0.0f);                      /* -log2e*relu(.) */             \
    const float d  = __builtin_amdgcn_exp2f(z);                               \
    const float p2 = qperm<0x4E>(v);                                          \
    const float fv = (tt == 1) ? v : p2;                                      \
    const float r  = odd ? fv * (d * (CVAR)) : v * p2;                        \
    const float cn = r + qperm<0xB1>(r);                                      \
    (CVAR) = cn;                                                              \
    const float e2 = __builtin_amdgcn_exp2f(-2.0f * LOG2E * cn);              \
    const float th = fmaf(2.0f, __builtin_amdgcn_rcpf(1.0f + e2), -1.0f);     \
    (HVAR) = v * th;                                                          \
  }

__global__ __launch_bounds__(512, 2) void lstm_rev(
    const _Float16* __restrict__ gx,        // [S*B][512] f16, pre-scaled
    const float* __restrict__ timep,        // [S*B]
    const float* __restrict__ Whh,          // [512][128]
    const float* __restrict__ w_tp,         // [128]
    const float* __restrict__ b_tp,         // [128]
    float* __restrict__ out)                // S*B*H outputs, then h, then c
{
  __shared__ __align__(16) _Float16 hbuf[2][2][H_SZ];  // [batch][pingpong][col]
  const int tid = threadIdx.x;
  const int b0  = blockIdx.x * 2;            // this WG's two batches
  const int tt  = tid & 3;
  const int col = tid >> 2;
  const int j   = tt * 128 + col;

  const float LOG2E = 1.4426950408889634f;

  // Pre-scaled f16 weights in 16 NAMED registers: wTI = sc(T) *
  // W_hh[T*128+col][I*32+tt*8 .. +7].  Shared by both batches.
  half8 w00, w01, w02, w03, w10, w11, w12, w13;
  half8 w20, w21, w22, w23, w30, w31, w32, w33;
  {
    const float s1 = -LOG2E, s2 = -2.0f * LOG2E;
    const float* r0 = Whh + (size_t)(0 * 128 + col) * H_SZ + tt * 8;
    const float* r1 = Whh + (size_t)(1 * 128 + col) * H_SZ + tt * 8;
    const float* r2 = Whh + (size_t)(2 * 128 + col) * H_SZ + tt * 8;
    const float* r3 = Whh + (size_t)(3 * 128 + col) * H_SZ + tt * 8;
    w00 = wcvt(r0 +  0, s1); w01 = wcvt(r0 + 32, s1);
    w02 = wcvt(r0 + 64, s1); w03 = wcvt(r0 + 96, s1);
    w10 = wcvt(r1 +  0, s1); w11 = wcvt(r1 + 32, s1);
    w12 = wcvt(r1 + 64, s1); w13 = wcvt(r1 + 96, s1);
    w20 = wcvt(r2 +  0, s2); w21 = wcvt(r2 + 32, s2);
    w22 = wcvt(r2 + 64, s2); w23 = wcvt(r2 + 96, s2);
    w30 = wcvt(r3 +  0, s1); w31 = wcvt(r3 + 32, s1);
    w32 = wcvt(r3 + 64, s1); w33 = wcvt(r3 + 96, s1);
  }

  const float wt = -LOG2E * w_tp[col];
  const float bt = -LOG2E * b_tp[col];
  const float am  = (tt == 2) ? 2.0f : 1.0f;
  const float aa  = (tt == 2) ? -1.0f : 0.0f;
  const bool  odd = (tt & 1) != 0;

  ((_Float16*)hbuf)[tid] = (_Float16)0.0f;   // 512 entries == 512 threads
  __syncthreads();

  // gx element index for row t: (t<<15) + go{0,1}   (B*G4 = 32768 = 1<<15)
  const size_t go0 = (size_t)b0 * G4 + j;
  const size_t go1 = go0 + G4;

  // distance-2 prefetch: r0* = row t (ready), r1* = row t-1 (in flight)
  _Float16 r0a = gx[((size_t)(S_LEN - 1) << 15) + go0];
  _Float16 r0b = gx[((size_t)(S_LEN - 1) << 15) + go1];
  _Float16 r1a = gx[((size_t)(S_LEN - 2) << 15) + go0];
  _Float16 r1b = gx[((size_t)(S_LEN - 2) << 15) + go1];
  floatx2 tm0 = *(const floatx2*)(timep + ((S_LEN - 1) << 6) + b0);
  floatx2 tm1 = *(const floatx2*)(timep + ((S_LEN - 2) << 6) + b0);

  float c0 = 0.0f, c1 = 0.0f;

  for (int t = S_LEN - 1; t > 0; t -= 2) {
    // ---- substep A: T = t, read pingpong 0, write pingpong 1 ----
    {
      const int tl = (t >= 2) ? (t - 2) : 0;
      _Float16 r2a = gx[((size_t)tl << 15) + go0];
      _Float16 r2b = gx[((size_t)tl << 15) + go1];
      floatx2 tm2 = *(const floatx2*)(timep + (tl << 6) + b0);
      const float g0 = (float)r0a;
      const float g1 = (float)r0b;
      float h0, h1;
      GATE(&hbuf[0][0][0], g0, tm0.x, c0, h0);
      GATE(&hbuf[1][0][0], g1, tm0.y, c1, h1);
      if (tt == 3) {
        hbuf[0][1][col] = (_Float16)h0;
        hbuf[1][1][col] = (_Float16)h1;
        float* o = out + ((size_t)t << 13) + (size_t)b0 * H_SZ + col;
        o[0]    = h0;
        o[H_SZ] = h1;
      }
      lds_barrier();
      r0a = r1a; r0b = r1b; r1a = r2a; r1b = r2b;
      tm0 = tm1; tm1 = tm2;
    }
    // ---- substep B: T = t-1, read pingpong 1, write pingpong 0 ----
    {
      const int T  = t - 1;
      const int tl = (T >= 2) ? (T - 2) : 0;
      _Float16 r2a = gx[((size_t)tl << 15) + go0];
      _Float16 r2b = gx[((size_t)tl << 15) + go1];
      floatx2 tm2 = *(const floatx2*)(timep + (tl << 6) + b0);
      const float g0 = (float)r0a;
      const float g1 = (float)r0b;
      float h0, h1;
      GATE(&hbuf[0][1][0], g0, tm0.x, c0, h0);
      GATE(&hbuf[1][1][0], g1, tm0.y, c1, h1);
      if (tt == 3) {
        hbuf[0][0][col] = (_Float16)h0;
        hbuf[1][0][col] = (_Float16)h1;
        float* o = out + ((size_t)T << 13) + (size_t)b0 * H_SZ + col;
        o[0]    = h0;
        o[H_SZ] = h1;
        if (T == 0) {
          float* hf = out + (size_t)S_LEN * B_SZ * H_SZ;
          hf[(size_t)b0 * H_SZ + col]       = h0;
          hf[(size_t)(b0 + 1) * H_SZ + col] = h1;
          float* cf = hf + (size_t)B_SZ * H_SZ;
          cf[(size_t)b0 * H_SZ + col]       = c0;
          cf[(size_t)(b0 + 1) * H_SZ + col] = c1;
        }
      }
      lds_barrier();
      r0a = r1a; r0b = r1b; r1a = r2a; r1b = r2b;
      tm0 = tm1; tm1 = tm2;
    }
  }
}

// ---------------------------------------------------------------------------
extern "C" void kernel_launch(void* const* d_in, const int* in_sizes, int n_in,
                              void* d_out, int out_size, void* d_ws, size_t ws_size,
                              hipStream_t stream) {
  const float* input = (const float*)d_in[0];   // (S,B,D)
  const float* timep = (const float*)d_in[1];   // (S,B,1)
  const float* W_ih  = (const float*)d_in[2];   // (4H,D)
  const float* W_hh  = (const float*)d_in[3];   // (4H,H)
  const float* bias  = (const float*)d_in[4];   // (4H,)
  const float* w_t   = (const float*)d_in[5];   // (H,)
  const float* b_t   = (const float*)d_in[6];   // (H,)
  float* out = (float*)d_out;

  _Float16* gx = (_Float16*)d_ws;   // 2048*64*512*2 = 128 MiB

  gx_gemm<<<dim3((S_LEN * B_SZ) / 256), dim3(256), 0, stream>>>(
      input, W_ih, bias, gx);

  lstm_rev<<<dim3(B_SZ / 2), dim3(512), 0, stream>>>(
      gx, timep, W_hh, w_t, b_t, out);
}

// Round 4
// 1377.258 us; speedup vs baseline: 1.7563x; 1.7563x over previous
//
#include <hip/hip_runtime.h>

#define S_LEN 2048
#define B_SZ  64
#define D_IN  128
#define H_SZ  128
#define G4    512   // 4*H

typedef __attribute__((ext_vector_type(4))) float     floatx4;
typedef __attribute__((ext_vector_type(2))) float     floatx2;
typedef __attribute__((ext_vector_type(8))) _Float16  half8;
typedef __attribute__((ext_vector_type(2))) _Float16  half2_t;

// DPP quad_perm helper (VALU pipe). CTRL: xor1=0xB1, xor2=0x4E.
template<int CTRL>
__device__ __forceinline__ float qperm(float v) {
  return __int_as_float(
      __builtin_amdgcn_mov_dpp(__float_as_int(v), CTRL, 0xF, 0xF, true));
}

// half2 extraction from half8 — register aliasing, no union round-trip
template<int P>
__device__ __forceinline__ half2_t h2ext(half8 v) {
  return __builtin_shufflevector(v, v, 2 * P, 2 * P + 1);
}

// Workgroup barrier that drains ONLY lgkmcnt (LDS), leaving global loads/
// stores (vmcnt) in flight. __syncthreads() would drain vmcnt(0) each step.
__device__ __forceinline__ void lds_barrier() {
  asm volatile("s_waitcnt lgkmcnt(0)\n\ts_barrier" ::: "memory");
}

// ---------------------------------------------------------------------------
// Kernel 1: gates_x[sb][n] = (sum_k X[sb][k]*W_ih[n][k] + b[n]) * sc(type),
// stored f16.  sc = -log2e for i,f,o; -2log2e for g (folds the sigmoid/tanh
// exp2 scaling into the data so lstm_rev's activation chain is shorter).
// ---------------------------------------------------------------------------
__global__ __launch_bounds__(256) void gx_gemm(
    const float* __restrict__ X,       // [S*B][128]
    const float* __restrict__ Wih,     // [512][128]
    const float* __restrict__ bias,    // [512]
    _Float16* __restrict__ gx)         // [S*B][512] f16, pre-scaled
{
  __shared__ _Float16 Wl[128][136];
  const int tid  = threadIdx.x;
  const int lane = tid & 63;
  const int wv   = tid >> 6;
  const int R0   = blockIdx.x * 256;
  const int m    = lane & 15;
  const int q    = lane >> 4;

  const float LOG2E = 1.4426950408889634f;

  half8 afrag[4][4];
  #pragma unroll
  for (int rg = 0; rg < 4; ++rg) {
    const float* xrow = X + (size_t)(R0 + rg * 64 + wv * 16 + m) * D_IN;
    #pragma unroll
    for (int kf = 0; kf < 4; ++kf) {
      const int k0 = kf * 32 + q * 8;
      floatx4 v0 = *(const floatx4*)(xrow + k0);
      floatx4 v1 = *(const floatx4*)(xrow + k0 + 4);
      half8 a;
      a[0] = (_Float16)v0.x; a[1] = (_Float16)v0.y;
      a[2] = (_Float16)v0.z; a[3] = (_Float16)v0.w;
      a[4] = (_Float16)v1.x; a[5] = (_Float16)v1.y;
      a[6] = (_Float16)v1.z; a[7] = (_Float16)v1.w;
      afrag[rg][kf] = a;
    }
  }

  for (int nc = 0; nc < 4; ++nc) {      // gate-type chunk (128 gate rows)
    const float sc = (nc == 2) ? (-2.0f * LOG2E) : (-LOG2E);
    __syncthreads();
    for (int i = tid; i < 128 * 32; i += 256) {
      const int row = i >> 5;
      const int c4  = (i & 31) * 4;
      floatx4 v = *(const floatx4*)(Wih + ((size_t)nc * 128 + row) * D_IN + c4);
      Wl[row][c4 + 0] = (_Float16)v.x;
      Wl[row][c4 + 1] = (_Float16)v.y;
      Wl[row][c4 + 2] = (_Float16)v.z;
      Wl[row][c4 + 3] = (_Float16)v.w;
    }
    __syncthreads();

    #pragma unroll
    for (int nt = 0; nt < 8; ++nt) {
      const int n0  = nc * 128 + nt * 16;
      const int nlo = nt * 16 + m;
      const float bv = bias[n0 + m];
      half8 bfrag[4];
      #pragma unroll
      for (int kf = 0; kf < 4; ++kf)
        bfrag[kf] = *(const half8*)(&Wl[nlo][kf * 32 + q * 8]);
      #pragma unroll
      for (int rg = 0; rg < 4; ++rg) {
        floatx4 acc = {bv, bv, bv, bv};
        #pragma unroll
        for (int kf = 0; kf < 4; ++kf)
          acc = __builtin_amdgcn_mfma_f32_16x16x32_f16(afrag[rg][kf],
                                                       bfrag[kf], acc, 0, 0, 0);
        // C layout: col = lane&15, row = q*4 + reg
        _Float16* gp =
            gx + (size_t)(R0 + rg * 64 + wv * 16 + q * 4) * G4 + n0 + m;
        #pragma unroll
        for (int r = 0; r < 4; ++r)
          gp[(size_t)r * G4] = (_Float16)(acc[r] * sc);
      }
    }
  }
}

// ---------------------------------------------------------------------------
// Kernel 2: reverse-time recurrence. One WG per batch (64 WGs x 512 thr).
//
// KEY FIX (round 3/4): rounds 0-2 all allocated only 60 VGPRs — the 64
// VGPRs of W_hh f16 weights were being spill-reloaded from scratch EVERY
// substep (~256 B/thread/substep on the serial critical path; VALUBusy 9%).
// The allocator targets 8-waves/EU occupancy the 64-WG grid can never use.
// PIN_WEIGHTS() — an empty asm with "+v" constraints on all 16 weight
// vectors — forces them to be VGPR-resident at two points in every loop
// iteration, making the spill strictly unprofitable. Validity gate:
// VGPR_Count must jump to >=120.
// types: 0=i 1=f 2=g 3=o
// ---------------------------------------------------------------------------
__device__ __forceinline__ float fd(half2_t a, half2_t b, float c) {
  return __builtin_amdgcn_fdot2(a, b, c, false);
}

__device__ __forceinline__ half8 wcvt(const float* __restrict__ p, float sc) {
  floatx4 v0 = *(const floatx4*)p;
  floatx4 v1 = *(const floatx4*)(p + 4);
  half8 h;
  h[0] = (_Float16)(v0.x * sc); h[1] = (_Float16)(v0.y * sc);
  h[2] = (_Float16)(v0.z * sc); h[3] = (_Float16)(v0.w * sc);
  h[4] = (_Float16)(v1.x * sc); h[5] = (_Float16)(v1.y * sc);
  h[6] = (_Float16)(v1.z * sc); h[7] = (_Float16)(v1.w * sc);
  return h;
}

#define PIN_WEIGHTS()                                                         \
  asm volatile(""                                                             \
               : "+v"(w00), "+v"(w01), "+v"(w02), "+v"(w03),                  \
                 "+v"(w10), "+v"(w11), "+v"(w12), "+v"(w13),                  \
                 "+v"(w20), "+v"(w21), "+v"(w22), "+v"(w23),                  \
                 "+v"(w30), "+v"(w31), "+v"(w32), "+v"(w33),                  \
                 "+v"(wt), "+v"(bt))

// DOT8 over one h-fragment HV with the four gate-type weight frags WA..WD
// (WA = gate i, WB = f, WC = g, WD = o).
#define DOT8(HV, WA, WB, WC, WD)                                              \
  {                                                                           \
    q0a = fd(h2ext<0>(HV), h2ext<0>(WA), q0a);                                \
    q1a = fd(h2ext<0>(HV), h2ext<0>(WB), q1a);                                \
    q2a = fd(h2ext<0>(HV), h2ext<0>(WC), q2a);                                \
    q3a = fd(h2ext<0>(HV), h2ext<0>(WD), q3a);                                \
    q0a = fd(h2ext<1>(HV), h2ext<1>(WA), q0a);                                \
    q1a = fd(h2ext<1>(HV), h2ext<1>(WB), q1a);                                \
    q2a = fd(h2ext<1>(HV), h2ext<1>(WC), q2a);                                \
    q3a = fd(h2ext<1>(HV), h2ext<1>(WD), q3a);                                \
    q0b = fd(h2ext<2>(HV), h2ext<2>(WA), q0b);                                \
    q1b = fd(h2ext<2>(HV), h2ext<2>(WB), q1b);                                \
    q2b = fd(h2ext<2>(HV), h2ext<2>(WC), q2b);                                \
    q3b = fd(h2ext<2>(HV), h2ext<2>(WD), q3b);                                \
    q0b = fd(h2ext<3>(HV), h2ext<3>(WA), q0b);                                \
    q1b = fd(h2ext<3>(HV), h2ext<3>(WB), q1b);                                \
    q2b = fd(h2ext<3>(HV), h2ext<3>(WC), q2b);                                \
    q3b = fd(h2ext<3>(HV), h2ext<3>(WD), q3b);                                \
  }

// Full gate pipeline for one step. HR: LDS prev-h (128 halfs). GXV/TMV:
// prefetched gx (pre-scaled) and time. CVAR: running c (updated). HVAR:
// receives h (meaningful on tt==3 lanes). Weight/lane constants from
// enclosing scope.
#define GATE(HR, GXV, TMV, CVAR, HVAR)                                        \
  {                                                                           \
    half8 hv0 = *(const half8*)((HR) + 0 * 32 + tt * 8);                      \
    half8 hv1 = *(const half8*)((HR) + 1 * 32 + tt * 8);                      \
    half8 hv2 = *(const half8*)((HR) + 2 * 32 + tt * 8);                      \
    half8 hv3 = *(const half8*)((HR) + 3 * 32 + tt * 8);                      \
    float q0a = 0.f, q0b = 0.f, q1a = 0.f, q1b = 0.f;                         \
    float q2a = 0.f, q2b = 0.f, q3a = 0.f, q3b = 0.f;                         \
    DOT8(hv0, w00, w10, w20, w30);                                            \
    DOT8(hv1, w01, w11, w21, w31);                                            \
    DOT8(hv2, w02, w12, w22, w32);                                            \
    DOT8(hv3, w03, w13, w23, w33);                                            \
    float a0 = q0a + q0b, a1 = q1a + q1b, a2 = q2a + q2b, a3 = q3a + q3b;     \
    a0 += qperm<0xB1>(a0); a1 += qperm<0xB1>(a1);                             \
    a2 += qperm<0xB1>(a2); a3 += qperm<0xB1>(a3);                             \
    a0 += qperm<0x4E>(a0); a1 += qperm<0x4E>(a1);                             \
    a2 += qperm<0x4E>(a2); a3 += qperm<0x4E>(a3);                             \
    float pre = (tt & 1) ? ((tt & 2) ? a3 : a1) : ((tt & 2) ? a2 : a0);       \
    pre += (GXV);  /* already scaled by -log2e (or -2log2e for g) */          \
    const float e  = __builtin_amdgcn_exp2f(pre);                             \
    const float v  = fmaf(am, __builtin_amdgcn_rcpf(1.0f + e), aa);           \
    float z = fmaf((TMV), wt, bt);           /* = -log2e*(t*w_t+b_t) */       \
    z = fminf(z, 0.0f);                      /* -log2e*relu(.) */             \
    const float d  = __builtin_amdgcn_exp2f(z);                               \
    const float p2 = qperm<0x4E>(v);                                          \
    const float fv = (tt == 1) ? v : p2;                                      \
    const float r  = odd ? fv * (d * (CVAR)) : v * p2;                        \
    const float cn = r + qperm<0xB1>(r);                                      \
    (CVAR) = cn;                                                              \
    const float e2 = __builtin_amdgcn_exp2f(-2.0f * LOG2E * cn);              \
    const float th = fmaf(2.0f, __builtin_amdgcn_rcpf(1.0f + e2), -1.0f);     \
    (HVAR) = v * th;                                                          \
  }

__global__ __launch_bounds__(512, 2) void lstm_rev(
    const _Float16* __restrict__ gx,        // [S*B][512] f16, pre-scaled
    const float* __restrict__ timep,        // [S*B]
    const float* __restrict__ Whh,          // [512][128]
    const float* __restrict__ w_tp,         // [128]
    const float* __restrict__ b_tp,         // [128]
    float* __restrict__ out)                // S*B*H outputs, then h, then c
{
  __shared__ __align__(16) _Float16 hbuf[2][H_SZ];   // ping-pong prev-h
  const int tid = threadIdx.x;
  const int b   = blockIdx.x;                // one batch per WG
  const int tt  = tid & 3;
  const int col = tid >> 2;
  const int j   = tt * 128 + col;

  const float LOG2E = 1.4426950408889634f;

  // Pre-scaled f16 weights in 16 NAMED registers: wTI = sc(T) *
  // W_hh[T*128+col][I*32+tt*8 .. +7].
  half8 w00, w01, w02, w03, w10, w11, w12, w13;
  half8 w20, w21, w22, w23, w30, w31, w32, w33;
  {
    const float s1 = -LOG2E, s2 = -2.0f * LOG2E;
    const float* r0 = Whh + (size_t)(0 * 128 + col) * H_SZ + tt * 8;
    const float* r1 = Whh + (size_t)(1 * 128 + col) * H_SZ + tt * 8;
    const float* r2 = Whh + (size_t)(2 * 128 + col) * H_SZ + tt * 8;
    const float* r3 = Whh + (size_t)(3 * 128 + col) * H_SZ + tt * 8;
    w00 = wcvt(r0 +  0, s1); w01 = wcvt(r0 + 32, s1);
    w02 = wcvt(r0 + 64, s1); w03 = wcvt(r0 + 96, s1);
    w10 = wcvt(r1 +  0, s1); w11 = wcvt(r1 + 32, s1);
    w12 = wcvt(r1 + 64, s1); w13 = wcvt(r1 + 96, s1);
    w20 = wcvt(r2 +  0, s2); w21 = wcvt(r2 + 32, s2);
    w22 = wcvt(r2 + 64, s2); w23 = wcvt(r2 + 96, s2);
    w30 = wcvt(r3 +  0, s1); w31 = wcvt(r3 + 32, s1);
    w32 = wcvt(r3 + 64, s1); w33 = wcvt(r3 + 96, s1);
  }

  float wt = -LOG2E * w_tp[col];
  float bt = -LOG2E * b_tp[col];
  const float am  = (tt == 2) ? 2.0f : 1.0f;
  const float aa  = (tt == 2) ? -1.0f : 0.0f;
  const bool  odd = (tt & 1) != 0;

  if (tid < 2 * H_SZ) ((_Float16*)hbuf)[tid] = (_Float16)0.0f;
  __syncthreads();

  // gx element index for row t: (t<<15) + go   (B*G4 = 32768 = 1<<15)
  const size_t go = (size_t)b * G4 + j;

  // distance-2 prefetch: r0 = row t (ready), r1 = row t-1 (in flight)
  _Float16 r0 = gx[((size_t)(S_LEN - 1) << 15) + go];
  _Float16 r1 = gx[((size_t)(S_LEN - 2) << 15) + go];
  float tm0 = timep[((S_LEN - 1) << 6) + b];
  float tm1 = timep[((S_LEN - 2) << 6) + b];

  float c = 0.0f;

  for (int t = S_LEN - 1; t > 0; t -= 2) {
    PIN_WEIGHTS();
    // ---- substep A: T = t, read hbuf[0], write hbuf[1] ----
    {
      const int tl = (t >= 2) ? (t - 2) : 0;
      _Float16 r2 = gx[((size_t)tl << 15) + go];
      float   tm2 = timep[(tl << 6) + b];
      const float g0 = (float)r0;
      float h0;
      GATE(&hbuf[0][0], g0, tm0, c, h0);
      if (tt == 3) {
        hbuf[1][col] = (_Float16)h0;
        out[((size_t)t << 13) + (size_t)b * H_SZ + col] = h0;
      }
      lds_barrier();
      r0 = r1; r1 = r2; tm0 = tm1; tm1 = tm2;
    }
    PIN_WEIGHTS();
    // ---- substep B: T = t-1, read hbuf[1], write hbuf[0] ----
    {
      const int T  = t - 1;
      const int tl = (T >= 2) ? (T - 2) : 0;
      _Float16 r2 = gx[((size_t)tl << 15) + go];
      float   tm2 = timep[(tl << 6) + b];
      const float g0 = (float)r0;
      float h0;
      GATE(&hbuf[1][0], g0, tm0, c, h0);
      if (tt == 3) {
        hbuf[0][col] = (_Float16)h0;
        out[((size_t)T << 13) + (size_t)b * H_SZ + col] = h0;
        if (T == 0) {
          float* hf = out + (size_t)S_LEN * B_SZ * H_SZ;
          hf[(size_t)b * H_SZ + col] = h0;
          hf[(size_t)B_SZ * H_SZ + (size_t)b * H_SZ + col] = c;
        }
      }
      lds_barrier();
      r0 = r1; r1 = r2; tm0 = tm1; tm1 = tm2;
    }
  }
}

// ---------------------------------------------------------------------------
extern "C" void kernel_launch(void* const* d_in, const int* in_sizes, int n_in,
                              void* d_out, int out_size, void* d_ws, size_t ws_size,
                              hipStream_t stream) {
  const float* input = (const float*)d_in[0];   // (S,B,D)
  const float* timep = (const float*)d_in[1];   // (S,B,1)
  const float* W_ih  = (const float*)d_in[2];   // (4H,D)
  const float* W_hh  = (const float*)d_in[3];   // (4H,H)
  const float* bias  = (const float*)d_in[4];   // (4H,)
  const float* w_t   = (const float*)d_in[5];   // (H,)
  const float* b_t   = (const float*)d_in[6];   // (H,)
  float* out = (float*)d_out;

  _Float16* gx = (_Float16*)d_ws;   // 2048*64*512*2 = 128 MiB

  gx_gemm<<<dim3((S_LEN * B_SZ) / 256), dim3(256), 0, stream>>>(
      input, W_ih, bias, gx);

  lstm_rev<<<dim3(B_SZ), dim3(512), 0, stream>>>(
      gx, timep, W_hh, w_t, b_t, out);
}

// Round 5
// 1375.366 us; speedup vs baseline: 1.7588x; 1.0014x over previous
//
#include <hip/hip_runtime.h>

#define S_LEN 2048
#define B_SZ  64
#define D_IN  128
#define H_SZ  128
#define G4    512   // 4*H

typedef __attribute__((ext_vector_type(4))) float     floatx4;
typedef __attribute__((ext_vector_type(2))) float     floatx2;
typedef __attribute__((ext_vector_type(8))) _Float16  half8;
typedef __attribute__((ext_vector_type(2))) _Float16  half2_t;

// DPP quad_perm helper (VALU pipe). CTRL: xor1=0xB1, xor2=0x4E.
template<int CTRL>
__device__ __forceinline__ float qperm(float v) {
  return __int_as_float(
      __builtin_amdgcn_mov_dpp(__float_as_int(v), CTRL, 0xF, 0xF, true));
}

// half2 extraction from half8 — register aliasing, no union round-trip
template<int P>
__device__ __forceinline__ half2_t h2ext(half8 v) {
  return __builtin_shufflevector(v, v, 2 * P, 2 * P + 1);
}

// Workgroup barrier that drains ONLY lgkmcnt (LDS), leaving global loads/
// stores (vmcnt) in flight. __syncthreads() would drain vmcnt(0) each step.
__device__ __forceinline__ void lds_barrier() {
  asm volatile("s_waitcnt lgkmcnt(0)\n\ts_barrier" ::: "memory");
}

// ---------------------------------------------------------------------------
// Kernel 1: gates_x[sb][n] = (sum_k X[sb][k]*W_ih[n][k] + b[n]) * sc(type),
// stored f16.  sc = -log2e for i,f,o; -2log2e for g (folds the sigmoid/tanh
// exp2 scaling into the data so lstm_rev's activation chain is shorter).
// ---------------------------------------------------------------------------
__global__ __launch_bounds__(256) void gx_gemm(
    const float* __restrict__ X,       // [S*B][128]
    const float* __restrict__ Wih,     // [512][128]
    const float* __restrict__ bias,    // [512]
    _Float16* __restrict__ gx)         // [S*B][512] f16, pre-scaled
{
  __shared__ _Float16 Wl[128][136];
  const int tid  = threadIdx.x;
  const int lane = tid & 63;
  const int wv   = tid >> 6;
  const int R0   = blockIdx.x * 256;
  const int m    = lane & 15;
  const int q    = lane >> 4;

  const float LOG2E = 1.4426950408889634f;

  half8 afrag[4][4];
  #pragma unroll
  for (int rg = 0; rg < 4; ++rg) {
    const float* xrow = X + (size_t)(R0 + rg * 64 + wv * 16 + m) * D_IN;
    #pragma unroll
    for (int kf = 0; kf < 4; ++kf) {
      const int k0 = kf * 32 + q * 8;
      floatx4 v0 = *(const floatx4*)(xrow + k0);
      floatx4 v1 = *(const floatx4*)(xrow + k0 + 4);
      half8 a;
      a[0] = (_Float16)v0.x; a[1] = (_Float16)v0.y;
      a[2] = (_Float16)v0.z; a[3] = (_Float16)v0.w;
      a[4] = (_Float16)v1.x; a[5] = (_Float16)v1.y;
      a[6] = (_Float16)v1.z; a[7] = (_Float16)v1.w;
      afrag[rg][kf] = a;
    }
  }

  for (int nc = 0; nc < 4; ++nc) {      // gate-type chunk (128 gate rows)
    const float sc = (nc == 2) ? (-2.0f * LOG2E) : (-LOG2E);
    __syncthreads();
    for (int i = tid; i < 128 * 32; i += 256) {
      const int row = i >> 5;
      const int c4  = (i & 31) * 4;
      floatx4 v = *(const floatx4*)(Wih + ((size_t)nc * 128 + row) * D_IN + c4);
      Wl[row][c4 + 0] = (_Float16)v.x;
      Wl[row][c4 + 1] = (_Float16)v.y;
      Wl[row][c4 + 2] = (_Float16)v.z;
      Wl[row][c4 + 3] = (_Float16)v.w;
    }
    __syncthreads();

    #pragma unroll
    for (int nt = 0; nt < 8; ++nt) {
      const int n0  = nc * 128 + nt * 16;
      const int nlo = nt * 16 + m;
      const float bv = bias[n0 + m];
      half8 bfrag[4];
      #pragma unroll
      for (int kf = 0; kf < 4; ++kf)
        bfrag[kf] = *(const half8*)(&Wl[nlo][kf * 32 + q * 8]);
      #pragma unroll
      for (int rg = 0; rg < 4; ++rg) {
        floatx4 acc = {bv, bv, bv, bv};
        #pragma unroll
        for (int kf = 0; kf < 4; ++kf)
          acc = __builtin_amdgcn_mfma_f32_16x16x32_f16(afrag[rg][kf],
                                                       bfrag[kf], acc, 0, 0, 0);
        // C layout: col = lane&15, row = q*4 + reg
        _Float16* gp =
            gx + (size_t)(R0 + rg * 64 + wv * 16 + q * 4) * G4 + n0 + m;
        #pragma unroll
        for (int r = 0; r < 4; ++r)
          gp[(size_t)r * G4] = (_Float16)(acc[r] * sc);
      }
    }
  }
}

// ---------------------------------------------------------------------------
// Kernel 2: reverse-time recurrence. One WG per batch (64 WGs x 512 thr).
//
// ROUND 5 KEY FIX: __launch_bounds__(512,2) only sets a MINIMUM waves/EU —
// the allocator still targeted max occupancy (8 waves/EU => ~64-VGPR
// budget), so the 66 VGPRs of weights were remat-reloaded (global load +
// re-scale/convert) inside every GATE (round 4: VGPR=72 = weights live at
// the pins only; VALUBusy 18% half-spent on remat). With a 64-WG grid only
// 2 waves/EU are ever resident, so cap it: amdgpu_waves_per_eu(2,2) =>
// 256-VGPR budget => weights + working set (~110-140 VGPRs) fully resident.
// Validity gate: VGPR_Count >= 96.
// types: 0=i 1=f 2=g 3=o
// ---------------------------------------------------------------------------
__device__ __forceinline__ float fd(half2_t a, half2_t b, float c) {
  return __builtin_amdgcn_fdot2(a, b, c, false);
}

__device__ __forceinline__ half8 wcvt(const float* __restrict__ p, float sc) {
  floatx4 v0 = *(const floatx4*)p;
  floatx4 v1 = *(const floatx4*)(p + 4);
  half8 h;
  h[0] = (_Float16)(v0.x * sc); h[1] = (_Float16)(v0.y * sc);
  h[2] = (_Float16)(v0.z * sc); h[3] = (_Float16)(v0.w * sc);
  h[4] = (_Float16)(v1.x * sc); h[5] = (_Float16)(v1.y * sc);
  h[6] = (_Float16)(v1.z * sc); h[7] = (_Float16)(v1.w * sc);
  return h;
}

#define PIN_WEIGHTS()                                                         \
  asm volatile(""                                                             \
               : "+v"(w00), "+v"(w01), "+v"(w02), "+v"(w03),                  \
                 "+v"(w10), "+v"(w11), "+v"(w12), "+v"(w13),                  \
                 "+v"(w20), "+v"(w21), "+v"(w22), "+v"(w23),                  \
                 "+v"(w30), "+v"(w31), "+v"(w32), "+v"(w33),                  \
                 "+v"(wt), "+v"(bt))

// DOT8 over one h-fragment HV with the four gate-type weight frags WA..WD
// (WA = gate i, WB = f, WC = g, WD = o).
#define DOT8(HV, WA, WB, WC, WD)                                              \
  {                                                                           \
    q0a = fd(h2ext<0>(HV), h2ext<0>(WA), q0a);                                \
    q1a = fd(h2ext<0>(HV), h2ext<0>(WB), q1a);                                \
    q2a = fd(h2ext<0>(HV), h2ext<0>(WC), q2a);                                \
    q3a = fd(h2ext<0>(HV), h2ext<0>(WD), q3a);                                \
    q0a = fd(h2ext<1>(HV), h2ext<1>(WA), q0a);                                \
    q1a = fd(h2ext<1>(HV), h2ext<1>(WB), q1a);                                \
    q2a = fd(h2ext<1>(HV), h2ext<1>(WC), q2a);                                \
    q3a = fd(h2ext<1>(HV), h2ext<1>(WD), q3a);                                \
    q0b = fd(h2ext<2>(HV), h2ext<2>(WA), q0b);                                \
    q1b = fd(h2ext<2>(HV), h2ext<2>(WB), q1b);                                \
    q2b = fd(h2ext<2>(HV), h2ext<2>(WC), q2b);                                \
    q3b = fd(h2ext<2>(HV), h2ext<2>(WD), q3b);                                \
    q0b = fd(h2ext<3>(HV), h2ext<3>(WA), q0b);                                \
    q1b = fd(h2ext<3>(HV), h2ext<3>(WB), q1b);                                \
    q2b = fd(h2ext<3>(HV), h2ext<3>(WC), q2b);                                \
    q3b = fd(h2ext<3>(HV), h2ext<3>(WD), q3b);                                \
  }

// Full gate pipeline for one step. HR: LDS prev-h (128 halfs). GXV/TMV:
// prefetched gx (pre-scaled) and time. CVAR: running c (updated). HVAR:
// receives h (meaningful on tt==3 lanes). Weight/lane constants from
// enclosing scope.
#define GATE(HR, GXV, TMV, CVAR, HVAR)                                        \
  {                                                                           \
    half8 hv0 = *(const half8*)((HR) + 0 * 32 + tt * 8);                      \
    half8 hv1 = *(const half8*)((HR) + 1 * 32 + tt * 8);                      \
    half8 hv2 = *(const half8*)((HR) + 2 * 32 + tt * 8);                      \
    half8 hv3 = *(const half8*)((HR) + 3 * 32 + tt * 8);                      \
    float q0a = 0.f, q0b = 0.f, q1a = 0.f, q1b = 0.f;                         \
    float q2a = 0.f, q2b = 0.f, q3a = 0.f, q3b = 0.f;                         \
    DOT8(hv0, w00, w10, w20, w30);                                            \
    DOT8(hv1, w01, w11, w21, w31);                                            \
    DOT8(hv2, w02, w12, w22, w32);                                            \
    DOT8(hv3, w03, w13, w23, w33);                                            \
    float a0 = q0a + q0b, a1 = q1a + q1b, a2 = q2a + q2b, a3 = q3a + q3b;     \
    a0 += qperm<0xB1>(a0); a1 += qperm<0xB1>(a1);                             \
    a2 += qperm<0xB1>(a2); a3 += qperm<0xB1>(a3);                             \
    a0 += qperm<0x4E>(a0); a1 += qperm<0x4E>(a1);                             \
    a2 += qperm<0x4E>(a2); a3 += qperm<0x4E>(a3);                             \
    float pre = (tt & 1) ? ((tt & 2) ? a3 : a1) : ((tt & 2) ? a2 : a0);       \
    pre += (GXV);  /* already scaled by -log2e (or -2log2e for g) */          \
    const float e  = __builtin_amdgcn_exp2f(pre);                             \
    const float v  = fmaf(am, __builtin_amdgcn_rcpf(1.0f + e), aa);           \
    float z = fmaf((TMV), wt, bt);           /* = -log2e*(t*w_t+b_t) */       \
    z = fminf(z, 0.0f);                      /* -log2e*relu(.) */             \
    const float d  = __builtin_amdgcn_exp2f(z);                               \
    const float p2 = qperm<0x4E>(v);                                          \
    const float fv = (tt == 1) ? v : p2;                                      \
    const float r  = odd ? fv * (d * (CVAR)) : v * p2;                        \
    const float cn = r + qperm<0xB1>(r);                                      \
    (CVAR) = cn;                                                              \
    const float e2 = __builtin_amdgcn_exp2f(-2.0f * LOG2E * cn);              \
    const float th = fmaf(2.0f, __builtin_amdgcn_rcpf(1.0f + e2), -1.0f);     \
    (HVAR) = v * th;                                                          \
  }

__global__ __launch_bounds__(512)
__attribute__((amdgpu_waves_per_eu(2, 2)))
void lstm_rev(
    const _Float16* __restrict__ gx,        // [S*B][512] f16, pre-scaled
    const float* __restrict__ timep,        // [S*B]
    const float* __restrict__ Whh,          // [512][128]
    const float* __restrict__ w_tp,         // [128]
    const float* __restrict__ b_tp,         // [128]
    float* __restrict__ out)                // S*B*H outputs, then h, then c
{
  __shared__ __align__(16) _Float16 hbuf[2][H_SZ];   // ping-pong prev-h
  const int tid = threadIdx.x;
  const int b   = blockIdx.x;                // one batch per WG
  const int tt  = tid & 3;
  const int col = tid >> 2;
  const int j   = tt * 128 + col;

  const float LOG2E = 1.4426950408889634f;

  // Pre-scaled f16 weights in 16 NAMED registers: wTI = sc(T) *
  // W_hh[T*128+col][I*32+tt*8 .. +7].
  half8 w00, w01, w02, w03, w10, w11, w12, w13;
  half8 w20, w21, w22, w23, w30, w31, w32, w33;
  {
    const float s1 = -LOG2E, s2 = -2.0f * LOG2E;
    const float* r0 = Whh + (size_t)(0 * 128 + col) * H_SZ + tt * 8;
    const float* r1 = Whh + (size_t)(1 * 128 + col) * H_SZ + tt * 8;
    const float* r2 = Whh + (size_t)(2 * 128 + col) * H_SZ + tt * 8;
    const float* r3 = Whh + (size_t)(3 * 128 + col) * H_SZ + tt * 8;
    w00 = wcvt(r0 +  0, s1); w01 = wcvt(r0 + 32, s1);
    w02 = wcvt(r0 + 64, s1); w03 = wcvt(r0 + 96, s1);
    w10 = wcvt(r1 +  0, s1); w11 = wcvt(r1 + 32, s1);
    w12 = wcvt(r1 + 64, s1); w13 = wcvt(r1 + 96, s1);
    w20 = wcvt(r2 +  0, s2); w21 = wcvt(r2 + 32, s2);
    w22 = wcvt(r2 + 64, s2); w23 = wcvt(r2 + 96, s2);
    w30 = wcvt(r3 +  0, s1); w31 = wcvt(r3 + 32, s1);
    w32 = wcvt(r3 + 64, s1); w33 = wcvt(r3 + 96, s1);
  }

  float wt = -LOG2E * w_tp[col];
  float bt = -LOG2E * b_tp[col];
  const float am  = (tt == 2) ? 2.0f : 1.0f;
  const float aa  = (tt == 2) ? -1.0f : 0.0f;
  const bool  odd = (tt & 1) != 0;

  if (tid < 2 * H_SZ) ((_Float16*)hbuf)[tid] = (_Float16)0.0f;
  __syncthreads();

  // gx element index for row t: (t<<15) + go   (B*G4 = 32768 = 1<<15)
  const size_t go = (size_t)b * G4 + j;

  // distance-2 prefetch: r0 = row t (ready), r1 = row t-1 (in flight)
  _Float16 r0 = gx[((size_t)(S_LEN - 1) << 15) + go];
  _Float16 r1 = gx[((size_t)(S_LEN - 2) << 15) + go];
  float tm0 = timep[((S_LEN - 1) << 6) + b];
  float tm1 = timep[((S_LEN - 2) << 6) + b];

  float c = 0.0f;

  for (int t = S_LEN - 1; t > 0; t -= 2) {
    PIN_WEIGHTS();
    // ---- substep A: T = t, read hbuf[0], write hbuf[1] ----
    {
      const int tl = (t >= 2) ? (t - 2) : 0;
      _Float16 r2 = gx[((size_t)tl << 15) + go];
      float   tm2 = timep[(tl << 6) + b];
      const float g0 = (float)r0;
      float h0;
      GATE(&hbuf[0][0], g0, tm0, c, h0);
      if (tt == 3) {
        hbuf[1][col] = (_Float16)h0;
        out[((size_t)t << 13) + (size_t)b * H_SZ + col] = h0;
      }
      lds_barrier();
      r0 = r1; r1 = r2; tm0 = tm1; tm1 = tm2;
    }
    PIN_WEIGHTS();
    // ---- substep B: T = t-1, read hbuf[1], write hbuf[0] ----
    {
      const int T  = t - 1;
      const int tl = (T >= 2) ? (T - 2) : 0;
      _Float16 r2 = gx[((size_t)tl << 15) + go];
      float   tm2 = timep[(tl << 6) + b];
      const float g0 = (float)r0;
      float h0;
      GATE(&hbuf[1][0], g0, tm0, c, h0);
      if (tt == 3) {
        hbuf[0][col] = (_Float16)h0;
        out[((size_t)T << 13) + (size_t)b * H_SZ + col] = h0;
        if (T == 0) {
          float* hf = out + (size_t)S_LEN * B_SZ * H_SZ;
          hf[(size_t)b * H_SZ + col] = h0;
          hf[(size_t)B_SZ * H_SZ + (size_t)b * H_SZ + col] = c;
        }
      }
      lds_barrier();
      r0 = r1; r1 = r2; tm0 = tm1; tm1 = tm2;
    }
  }
}

// ---------------------------------------------------------------------------
extern "C" void kernel_launch(void* const* d_in, const int* in_sizes, int n_in,
                              void* d_out, int out_size, void* d_ws, size_t ws_size,
                              hipStream_t stream) {
  const float* input = (const float*)d_in[0];   // (S,B,D)
  const float* timep = (const float*)d_in[1];   // (S,B,1)
  const float* W_ih  = (const float*)d_in[2];   // (4H,D)
  const float* W_hh  = (const float*)d_in[3];   // (4H,H)
  const float* bias  = (const float*)d_in[4];   // (4H,)
  const float* w_t   = (const float*)d_in[5];   // (H,)
  const float* b_t   = (const float*)d_in[6];   // (H,)
  float* out = (float*)d_out;

  _Float16* gx = (_Float16*)d_ws;   // 2048*64*512*2 = 128 MiB

  gx_gemm<<<dim3((S_LEN * B_SZ) / 256), dim3(256), 0, stream>>>(
      input, W_ih, bias, gx);

  lstm_rev<<<dim3(B_SZ), dim3(512), 0, stream>>>(
      gx, timep, W_hh, w_t, b_t, out);
}

// Round 6
// 1286.537 us; speedup vs baseline: 1.8802x; 1.0690x over previous
//
#include <hip/hip_runtime.h>

#define S_LEN 2048
#define B_SZ  64
#define D_IN  128
#define H_SZ  128
#define G4    512   // 4*H

typedef __attribute__((ext_vector_type(4))) float     floatx4;
typedef __attribute__((ext_vector_type(2))) float     floatx2;
typedef __attribute__((ext_vector_type(8))) _Float16  half8;
typedef __attribute__((ext_vector_type(4))) _Float16  half4;
typedef __attribute__((ext_vector_type(2))) _Float16  half2_t;

// DPP quad_perm helper (VALU pipe). CTRL: xor1=0xB1, xor2=0x4E.
template<int CTRL>
__device__ __forceinline__ float qperm(float v) {
  return __int_as_float(
      __builtin_amdgcn_mov_dpp(__float_as_int(v), CTRL, 0xF, 0xF, true));
}

// half2 extraction from half8 — register aliasing, no union round-trip
template<int P>
__device__ __forceinline__ half2_t h2ext(half8 v) {
  return __builtin_shufflevector(v, v, 2 * P, 2 * P + 1);
}

// Workgroup barrier that drains ONLY lgkmcnt (LDS), leaving global loads/
// stores (vmcnt) in flight. __syncthreads() would drain vmcnt(0) each step.
__device__ __forceinline__ void lds_barrier() {
  asm volatile("s_waitcnt lgkmcnt(0)\n\ts_barrier" ::: "memory");
}

// ---------------------------------------------------------------------------
// Kernel 1: gx[b][n][t] = (sum_k X[t,b][k]*W_ih[n][k] + b[n]) * sc(type),
// stored f16 TRANSPOSED to [B][512][S] so lstm_rev reads 8 timesteps per
// load.  sc = -log2e for i,f,o; -2log2e for g.  Grid: (S/256, B); each WG
// covers 256 consecutive t for ONE batch, so the 4 acc values per thread
// are 4 consecutive t -> one packed 8B store (coalescing preserved).
// ---------------------------------------------------------------------------
__global__ __launch_bounds__(256) void gx_gemm(
    const float* __restrict__ X,       // [S*B][128] (row = t*64+b)
    const float* __restrict__ Wih,     // [512][128]
    const float* __restrict__ bias,    // [512]
    _Float16* __restrict__ gx)         // [64][512][2048] f16, pre-scaled
{
  __shared__ _Float16 Wl[128][136];
  const int tid  = threadIdx.x;
  const int lane = tid & 63;
  const int wv   = tid >> 6;
  const int b    = blockIdx.y;         // batch
  const int T0   = blockIdx.x * 256;   // time block
  const int m    = lane & 15;
  const int q    = lane >> 4;

  const float LOG2E = 1.4426950408889634f;

  // A-fragments: 4 row-groups of 64 t each; A-row = t, X row = t*64+b
  half8 afrag[4][4];
  #pragma unroll
  for (int rg = 0; rg < 4; ++rg) {
    const int t = T0 + rg * 64 + wv * 16 + m;
    const float* xrow = X + ((size_t)t * B_SZ + b) * D_IN;
    #pragma unroll
    for (int kf = 0; kf < 4; ++kf) {
      const int k0 = kf * 32 + q * 8;
      floatx4 v0 = *(const floatx4*)(xrow + k0);
      floatx4 v1 = *(const floatx4*)(xrow + k0 + 4);
      half8 a;
      a[0] = (_Float16)v0.x; a[1] = (_Float16)v0.y;
      a[2] = (_Float16)v0.z; a[3] = (_Float16)v0.w;
      a[4] = (_Float16)v1.x; a[5] = (_Float16)v1.y;
      a[6] = (_Float16)v1.z; a[7] = (_Float16)v1.w;
      afrag[rg][kf] = a;
    }
  }

  for (int nc = 0; nc < 4; ++nc) {      // gate-type chunk (128 gate rows)
    const float sc = (nc == 2) ? (-2.0f * LOG2E) : (-LOG2E);
    __syncthreads();
    for (int i = tid; i < 128 * 32; i += 256) {
      const int row = i >> 5;
      const int c4  = (i & 31) * 4;
      floatx4 v = *(const floatx4*)(Wih + ((size_t)nc * 128 + row) * D_IN + c4);
      Wl[row][c4 + 0] = (_Float16)v.x;
      Wl[row][c4 + 1] = (_Float16)v.y;
      Wl[row][c4 + 2] = (_Float16)v.z;
      Wl[row][c4 + 3] = (_Float16)v.w;
    }
    __syncthreads();

    #pragma unroll
    for (int nt = 0; nt < 8; ++nt) {
      const int n0  = nc * 128 + nt * 16;
      const int nlo = nt * 16 + m;
      const float bv = bias[n0 + m];
      half8 bfrag[4];
      #pragma unroll
      for (int kf = 0; kf < 4; ++kf)
        bfrag[kf] = *(const half8*)(&Wl[nlo][kf * 32 + q * 8]);
      #pragma unroll
      for (int rg = 0; rg < 4; ++rg) {
        floatx4 acc = {bv, bv, bv, bv};
        #pragma unroll
        for (int kf = 0; kf < 4; ++kf)
          acc = __builtin_amdgcn_mfma_f32_16x16x32_f16(afrag[rg][kf],
                                                       bfrag[kf], acc, 0, 0, 0);
        // C layout: col(n) = lane&15, row(t offset) = q*4 + reg
        // -> 4 consecutive t: pack into one 8B store at [b][n0+m][t]
        const int tbase = T0 + rg * 64 + wv * 16 + q * 4;
        half4 hv;
        hv[0] = (_Float16)(acc[0] * sc);
        hv[1] = (_Float16)(acc[1] * sc);
        hv[2] = (_Float16)(acc[2] * sc);
        hv[3] = (_Float16)(acc[3] * sc);
        *(half4*)(gx + ((size_t)b * G4 + n0 + m) * S_LEN + tbase) = hv;
      }
    }
  }
}

// ---------------------------------------------------------------------------
// Kernel 2: reverse-time recurrence. One WG per batch (64 WGs x 512 thr).
//
// ROUND 6: rounds 4/5 identical at VGPR 72 vs 88 => not alloc-bound;
// latency-bound at ~36% true issue utilization. Remaining exposed latency:
// per-substep gx/timep global loads whose register rotation forced a vmcnt
// wait ~1 substep (~690cy) after issue < HBM ~900cy. Fix: gx transposed to
// [b][j][t] => ONE half8 load per 8 substeps, double-buffered 2 blocks
// (~16 substeps) ahead; timep staged once into LDS (broadcast ds_read).
// Per-substep global traffic: zero.
// types: 0=i 1=f 2=g 3=o
// ---------------------------------------------------------------------------
__device__ __forceinline__ float fd(half2_t a, half2_t b, float c) {
  return __builtin_amdgcn_fdot2(a, b, c, false);
}

__device__ __forceinline__ half8 wcvt(const float* __restrict__ p, float sc) {
  floatx4 v0 = *(const floatx4*)p;
  floatx4 v1 = *(const floatx4*)(p + 4);
  half8 h;
  h[0] = (_Float16)(v0.x * sc); h[1] = (_Float16)(v0.y * sc);
  h[2] = (_Float16)(v0.z * sc); h[3] = (_Float16)(v0.w * sc);
  h[4] = (_Float16)(v1.x * sc); h[5] = (_Float16)(v1.y * sc);
  h[6] = (_Float16)(v1.z * sc); h[7] = (_Float16)(v1.w * sc);
  return h;
}

#define PIN_WEIGHTS()                                                         \
  asm volatile(""                                                             \
               : "+v"(w00), "+v"(w01), "+v"(w02), "+v"(w03),                  \
                 "+v"(w10), "+v"(w11), "+v"(w12), "+v"(w13),                  \
                 "+v"(w20), "+v"(w21), "+v"(w22), "+v"(w23),                  \
                 "+v"(w30), "+v"(w31), "+v"(w32), "+v"(w33),                  \
                 "+v"(wt), "+v"(bt))

// DOT8 over one h-fragment HV with the four gate-type weight frags WA..WD
#define DOT8(HV, WA, WB, WC, WD)                                              \
  {                                                                           \
    q0a = fd(h2ext<0>(HV), h2ext<0>(WA), q0a);                                \
    q1a = fd(h2ext<0>(HV), h2ext<0>(WB), q1a);                                \
    q2a = fd(h2ext<0>(HV), h2ext<0>(WC), q2a);                                \
    q3a = fd(h2ext<0>(HV), h2ext<0>(WD), q3a);                                \
    q0a = fd(h2ext<1>(HV), h2ext<1>(WA), q0a);                                \
    q1a = fd(h2ext<1>(HV), h2ext<1>(WB), q1a);                                \
    q2a = fd(h2ext<1>(HV), h2ext<1>(WC), q2a);                                \
    q3a = fd(h2ext<1>(HV), h2ext<1>(WD), q3a);                                \
    q0b = fd(h2ext<2>(HV), h2ext<2>(WA), q0b);                                \
    q1b = fd(h2ext<2>(HV), h2ext<2>(WB), q1b);                                \
    q2b = fd(h2ext<2>(HV), h2ext<2>(WC), q2b);                                \
    q3b = fd(h2ext<2>(HV), h2ext<2>(WD), q3b);                                \
    q0b = fd(h2ext<3>(HV), h2ext<3>(WA), q0b);                                \
    q1b = fd(h2ext<3>(HV), h2ext<3>(WB), q1b);                                \
    q2b = fd(h2ext<3>(HV), h2ext<3>(WC), q2b);                                \
    q3b = fd(h2ext<3>(HV), h2ext<3>(WD), q3b);                                \
  }

// Full gate pipeline for one step. HR: LDS prev-h (128 halfs). GXV/TMV:
// gate-x (pre-scaled, from register block) and time. CVAR: running c.
// HVAR: receives h (meaningful on tt==3 lanes).
#define GATE(HR, GXV, TMV, CVAR, HVAR)                                        \
  {                                                                           \
    half8 hv0 = *(const half8*)((HR) + 0 * 32 + tt * 8);                      \
    half8 hv1 = *(const half8*)((HR) + 1 * 32 + tt * 8);                      \
    half8 hv2 = *(const half8*)((HR) + 2 * 32 + tt * 8);                      \
    half8 hv3 = *(const half8*)((HR) + 3 * 32 + tt * 8);                      \
    float q0a = 0.f, q0b = 0.f, q1a = 0.f, q1b = 0.f;                         \
    float q2a = 0.f, q2b = 0.f, q3a = 0.f, q3b = 0.f;                         \
    DOT8(hv0, w00, w10, w20, w30);                                            \
    DOT8(hv1, w01, w11, w21, w31);                                            \
    DOT8(hv2, w02, w12, w22, w32);                                            \
    DOT8(hv3, w03, w13, w23, w33);                                            \
    float a0 = q0a + q0b, a1 = q1a + q1b, a2 = q2a + q2b, a3 = q3a + q3b;     \
    a0 += qperm<0xB1>(a0); a1 += qperm<0xB1>(a1);                             \
    a2 += qperm<0xB1>(a2); a3 += qperm<0xB1>(a3);                             \
    a0 += qperm<0x4E>(a0); a1 += qperm<0x4E>(a1);                             \
    a2 += qperm<0x4E>(a2); a3 += qperm<0x4E>(a3);                             \
    float pre = (tt & 1) ? ((tt & 2) ? a3 : a1) : ((tt & 2) ? a2 : a0);       \
    pre += (GXV);  /* already scaled by -log2e (or -2log2e for g) */          \
    const float e  = __builtin_amdgcn_exp2f(pre);                             \
    const float v  = fmaf(am, __builtin_amdgcn_rcpf(1.0f + e), aa);           \
    float z = fmaf((TMV), wt, bt);           /* = -log2e*(t*w_t+b_t) */       \
    z = fminf(z, 0.0f);                      /* -log2e*relu(.) */             \
    const float d  = __builtin_amdgcn_exp2f(z);                               \
    const float p2 = qperm<0x4E>(v);                                          \
    const float fv = (tt == 1) ? v : p2;                                      \
    const float r  = odd ? fv * (d * (CVAR)) : v * p2;                        \
    const float cn = r + qperm<0xB1>(r);                                      \
    (CVAR) = cn;                                                              \
    const float e2 = __builtin_amdgcn_exp2f(-2.0f * LOG2E * cn);              \
    const float th = fmaf(2.0f, __builtin_amdgcn_rcpf(1.0f + e2), -1.0f);     \
    (HVAR) = v * th;                                                          \
  }

// One substep: K = index into cur8 (t = blk*8+K), TMV = staged time value,
// RP/WP = hbuf ping-pong read/write indices.
#define SUB(K, TMV, RP, WP)                                                   \
  {                                                                           \
    const float g0 = (float)cur8[K];                                          \
    float h0;                                                                 \
    GATE(&hbuf[RP][0], g0, (TMV), c, h0);                                     \
    if (tt == 3) {                                                            \
      hbuf[WP][col] = (_Float16)h0;                                           \
      const int tcur = blk * 8 + K;                                           \
      out[((size_t)tcur << 13) + bH + col] = h0;                              \
      if (tcur == 0) {                                                        \
        float* hf = out + (size_t)S_LEN * B_SZ * H_SZ;                        \
        hf[bH + col] = h0;                                                    \
        hf[(size_t)B_SZ * H_SZ + bH + col] = c;                               \
      }                                                                       \
    }                                                                         \
    lds_barrier();                                                            \
  }

__global__ __launch_bounds__(512)
__attribute__((amdgpu_waves_per_eu(2, 2)))
void lstm_rev(
    const _Float16* __restrict__ gx,        // [64][512][2048] f16, pre-scaled
    const float* __restrict__ timep,        // [S*B]
    const float* __restrict__ Whh,          // [512][128]
    const float* __restrict__ w_tp,         // [128]
    const float* __restrict__ b_tp,         // [128]
    float* __restrict__ out)                // S*B*H outputs, then h, then c
{
  __shared__ __align__(16) _Float16 hbuf[2][H_SZ];   // ping-pong prev-h
  __shared__ __align__(16) float    tml[S_LEN];      // staged timep[.,b] 8KB
  const int tid = threadIdx.x;
  const int b   = blockIdx.x;                // one batch per WG
  const int tt  = tid & 3;
  const int col = tid >> 2;
  const int j   = tt * 128 + col;

  const float LOG2E = 1.4426950408889634f;

  // Stage this batch's time column into LDS (one-time, 4 loads/thread).
  #pragma unroll
  for (int k = 0; k < 4; ++k) {
    const int idx = tid + k * 512;
    tml[idx] = timep[(idx << 6) + b];
  }

  // Pre-scaled f16 weights in 16 NAMED registers: wTI = sc(T) *
  // W_hh[T*128+col][I*32+tt*8 .. +7].
  half8 w00, w01, w02, w03, w10, w11, w12, w13;
  half8 w20, w21, w22, w23, w30, w31, w32, w33;
  {
    const float s1 = -LOG2E, s2 = -2.0f * LOG2E;
    const float* r0 = Whh + (size_t)(0 * 128 + col) * H_SZ + tt * 8;
    const float* r1 = Whh + (size_t)(1 * 128 + col) * H_SZ + tt * 8;
    const float* r2 = Whh + (size_t)(2 * 128 + col) * H_SZ + tt * 8;
    const float* r3 = Whh + (size_t)(3 * 128 + col) * H_SZ + tt * 8;
    w00 = wcvt(r0 +  0, s1); w01 = wcvt(r0 + 32, s1);
    w02 = wcvt(r0 + 64, s1); w03 = wcvt(r0 + 96, s1);
    w10 = wcvt(r1 +  0, s1); w11 = wcvt(r1 + 32, s1);
    w12 = wcvt(r1 + 64, s1); w13 = wcvt(r1 + 96, s1);
    w20 = wcvt(r2 +  0, s2); w21 = wcvt(r2 + 32, s2);
    w22 = wcvt(r2 + 64, s2); w23 = wcvt(r2 + 96, s2);
    w30 = wcvt(r3 +  0, s1); w31 = wcvt(r3 + 32, s1);
    w32 = wcvt(r3 + 64, s1); w33 = wcvt(r3 + 96, s1);
  }

  float wt = -LOG2E * w_tp[col];
  float bt = -LOG2E * b_tp[col];
  const float am  = (tt == 2) ? 2.0f : 1.0f;
  const float aa  = (tt == 2) ? -1.0f : 0.0f;
  const bool  odd = (tt & 1) != 0;

  if (tid < 2 * H_SZ) ((_Float16*)hbuf)[tid] = (_Float16)0.0f;
  __syncthreads();

  // This thread's gate-x row: 2048 consecutive f16 (one per t).
  const _Float16* gxr = gx + ((size_t)b * G4 + j) * S_LEN;
  const size_t bH = (size_t)b * H_SZ;

  // Double-buffered half8 blocks, 2 blocks (~16 substeps) ahead of use.
  half8 cur8 = *(const half8*)(gxr + 255 * 8);
  half8 nxt8 = *(const half8*)(gxr + 254 * 8);

  float c = 0.0f;

  for (int blk = 255; blk >= 0; --blk) {
    PIN_WEIGHTS();
    const int pfb = (blk >= 2) ? blk - 2 : 0;
    half8 fut8 = *(const half8*)(gxr + pfb * 8);
    const floatx4 tmA = *(const floatx4*)(&tml[blk * 8 + 4]); // t = +4..+7
    const floatx4 tmB = *(const floatx4*)(&tml[blk * 8 + 0]); // t = +0..+3

    // 8 substeps: t = blk*8+7 down to blk*8 (ping-pong parity returns to 0)
    SUB(7, tmA.w, 0, 1)
    SUB(6, tmA.z, 1, 0)
    SUB(5, tmA.y, 0, 1)
    SUB(4, tmA.x, 1, 0)
    SUB(3, tmB.w, 0, 1)
    SUB(2, tmB.z, 1, 0)
    SUB(1, tmB.y, 0, 1)
    SUB(0, tmB.x, 1, 0)

    cur8 = nxt8;
    nxt8 = fut8;
  }
}

// ---------------------------------------------------------------------------
extern "C" void kernel_launch(void* const* d_in, const int* in_sizes, int n_in,
                              void* d_out, int out_size, void* d_ws, size_t ws_size,
                              hipStream_t stream) {
  const float* input = (const float*)d_in[0];   // (S,B,D)
  const float* timep = (const float*)d_in[1];   // (S,B,1)
  const float* W_ih  = (const float*)d_in[2];   // (4H,D)
  const float* W_hh  = (const float*)d_in[3];   // (4H,H)
  const float* bias  = (const float*)d_in[4];   // (4H,)
  const float* w_t   = (const float*)d_in[5];   // (H,)
  const float* b_t   = (const float*)d_in[6];   // (H,)
  float* out = (float*)d_out;

  _Float16* gx = (_Float16*)d_ws;   // 64*512*2048*2 = 128 MiB, [b][n][t]

  gx_gemm<<<dim3(S_LEN / 256, B_SZ), dim3(256), 0, stream>>>(
      input, W_ih, bias, gx);

  lstm_rev<<<dim3(B_SZ), dim3(512), 0, stream>>>(
      gx, timep, W_hh, w_t, b_t, out);
}